// Round 7
// baseline (172.094 us; speedup 1.0000x reference)
//
#include <hip/hip_runtime.h>

// NRI MLP decoder, round 7: prep kernel (V/P -> ws f16) + deep main kernel.
// B=8, N=64, T=50 (49 used), D=4, H=64, K=2 (only relation i=1), E=4032.
// K1: grid 8*49*8, 64 thr: V[b,t,s,k]=x[s]·W1s[k], P[b,t,n,k]=b1[k]+x[n]·W1r[k].
// K2: grid 8*49*16, 256 thr (4 waves). Block=(b,t,4 receivers); wave=one
// 16-sender tile for all 4 receivers. Edge phase loads V/P frags DIRECTLY
// from global (L2-hot) -- no LDS, no barrier. Cross-wave agg reduce in LDS,
// then 3-layer node MLP (stride-68 f16 LDS). mfma_f32_16x16x32_f16, fp32 acc.

#define NB 8
#define NN 64
#define NT 50
#define NTO 49
#define ND 4
#define NE 4032

typedef _Float16 f16x8 __attribute__((ext_vector_type(8)));
typedef _Float16 f16x2 __attribute__((ext_vector_type(2)));
typedef float f32x4 __attribute__((ext_vector_type(4)));

union Frag8 { unsigned u[4]; f16x8 f; f16x2 h[4]; };

__device__ __forceinline__ unsigned pk16(float lo, float hi) {
  return __builtin_bit_cast(unsigned, __builtin_amdgcn_cvt_pkrtz(lo, hi));
}

#define MFMA16(A, B, C) __builtin_amdgcn_mfma_f32_16x16x32_f16((A), (B), (C), 0, 0, 0)

// ---------------------------------------------------------------------------
// K1: precompute V (64 sender rows) and P (64 receiver rows) per (b,t).
// bid -> (b, t, g); block covers 16 of the 128 rows; lane = k.
// ---------------------------------------------------------------------------
__global__ __launch_bounds__(64) void nri_prep_kernel(
    const float* __restrict__ inputs,  // (B,N,T,D)
    const float* __restrict__ fc1_w,   // (2,64,8)
    const float* __restrict__ fc1_b,   // (2,64)
    _Float16* __restrict__ Vg,         // (B,49,64,64) f16
    _Float16* __restrict__ Pg)         // (B,49,64,64) f16
{
  const int bid = blockIdx.x;
  const int g   = bid & 7;
  const int t   = (bid >> 3) % NTO;
  const int b   = bid / (8 * NTO);
  const int k   = threadIdx.x;

  const float4 w1r = *(const float4*)(fc1_w + 512 + k * 8);
  const float4 w1s = *(const float4*)(fc1_w + 516 + k * 8);
  const float  b1k = fc1_b[64 + k];
  const int bt64 = (b * NTO + t) * 64;

  if (g < 4) {  // V rows (g 0..3 -> s 0..63)
#pragma unroll
    for (int ii = 0; ii < 16; ++ii) {
      const int s = g * 16 + ii;
      const float4 x = *(const float4*)(inputs + ((b * NN + s) * NT + t) * ND);
      Vg[(bt64 + s) * 64 + k] =
          (_Float16)(w1s.x*x.x + w1s.y*x.y + w1s.z*x.z + w1s.w*x.w);
    }
  } else {      // P rows (g 4..7 -> n 0..63)
#pragma unroll
    for (int ii = 0; ii < 16; ++ii) {
      const int n = (g - 4) * 16 + ii;
      const float4 x = *(const float4*)(inputs + ((b * NN + n) * NT + t) * ND);
      Pg[(bt64 + n) * 64 + k] =
          (_Float16)(b1k + w1r.x*x.x + w1r.y*x.y + w1r.z*x.z + w1r.w*x.w);
    }
  }
}

// ---------------------------------------------------------------------------
// K2: edge + node. bid -> (b, t, tile of 4 receivers).
// ---------------------------------------------------------------------------
__global__ __launch_bounds__(256) void nri_main_kernel(
    const float* __restrict__ inputs,
    const float* __restrict__ rel_type, // (B,1,E,2)
    const float* __restrict__ fc2_w,    // (2,64,64)
    const float* __restrict__ fc2_b,    // (2,64)
    const float* __restrict__ out1_w,   // (64,68)
    const float* __restrict__ out1_b,
    const float* __restrict__ out2_w,   // (64,64)
    const float* __restrict__ out2_b,
    const float* __restrict__ out3_w,   // (4,64)
    const float* __restrict__ out3_b,
    const _Float16* __restrict__ Vg,
    const _Float16* __restrict__ Pg,
    float* __restrict__ out)            // (B,N,49,4)
{
  __shared__ float    AggP[4][4][64];   // [wave][ni][o] partial aggs
  __shared__ _Float16 AggH[16 * 68];    // rows 0..3 valid (stride 68: low-conflict)
  __shared__ _Float16 H1L[16 * 68];
  __shared__ _Float16 H2L[16 * 68];
  __shared__ float4   Xl[4];

  const int bid    = blockIdx.x;
  const int tile   = bid & 15;
  const int t      = (bid >> 4) % NTO;
  const int b      = bid / (16 * NTO);
  const int n_base = tile * 4;
  const int tid  = threadIdx.x;
  const int lane = tid & 63;
  const int w    = tid >> 6;
  const int q    = lane >> 4;
  const int r    = lane & 15;
  const int bt64 = (b * NTO + t) * 64;

  if (tid < 4)
    Xl[tid] = *(const float4*)(inputs + ((b * NN + n_base + tid) * NT + t) * ND);

  // ---- V frags for this wave's sender tile (senders w*16 + r)
  Frag8 va0, va1;
  {
    const _Float16* vp = Vg + (bt64 + w * 16 + r) * 64 + q * 8;
    va0.f = *(const f16x8*)vp;
    va1.f = *(const f16x8*)(vp + 32);
  }

  // ---- W2 (relation 1) f16 B-frags
  Frag8 bfr[4][2];
  float b2l[4];
#pragma unroll
  for (int nt = 0; nt < 4; ++nt) {
    const int o = nt * 16 + r;
    b2l[nt] = fc2_b[64 + o];
#pragma unroll
    for (int ks = 0; ks < 2; ++ks) {
      const float* p = fc2_w + 4096 + o * 64 + ks * 32 + q * 8;
      const float4 c0 = *(const float4*)p;
      const float4 c1 = *(const float4*)(p + 4);
      bfr[nt][ks].u[0] = pk16(c0.x, c0.y);
      bfr[nt][ks].u[1] = pk16(c0.z, c0.w);
      bfr[nt][ks].u[2] = pk16(c1.x, c1.y);
      bfr[nt][ks].u[3] = pk16(c1.z, c1.w);
    }
  }

  // ---------------- edge phase: 4 receivers, one sender tile ----------------
#pragma unroll
  for (int ni = 0; ni < 4; ++ni) {
    const int n = n_base + ni;
    Frag8 pa0, pa1;
    {
      const _Float16* pp = Pg + (bt64 + n) * 64 + q * 8;  // wave-uniform per q
      pa0.f = *(const f16x8*)pp;
      pa1.f = *(const f16x8*)(pp + 32);
    }
    // rt for the quad's 4 senders
    float rtf[4];
    const int s0 = w * 16 + q * 4;
#pragma unroll
    for (int e = 0; e < 4; ++e) {
      const int s = s0 + e;
      rtf[e] = (s == n) ? 0.f
             : rel_type[(b * NE + n * 63 + (s < n ? s : s - 1)) * 2 + 1];
    }

    // h = relu(P + V), packed f16
    Frag8 a0, a1;
    const f16x2 z = {(_Float16)0.f, (_Float16)0.f};
#pragma unroll
    for (int j = 0; j < 4; ++j) {
      a0.h[j] = __builtin_elementwise_max((f16x2)(pa0.h[j] + va0.h[j]), z);
      a1.h[j] = __builtin_elementwise_max((f16x2)(pa1.h[j] + va1.h[j]), z);
    }

    f32x4 d0 = {b2l[0], b2l[0], b2l[0], b2l[0]};
    f32x4 d1 = {b2l[1], b2l[1], b2l[1], b2l[1]};
    f32x4 d2 = {b2l[2], b2l[2], b2l[2], b2l[2]};
    f32x4 d3 = {b2l[3], b2l[3], b2l[3], b2l[3]};
    d0 = MFMA16(a0.f, bfr[0][0].f, d0); d0 = MFMA16(a1.f, bfr[0][1].f, d0);
    d1 = MFMA16(a0.f, bfr[1][0].f, d1); d1 = MFMA16(a1.f, bfr[1][1].f, d1);
    d2 = MFMA16(a0.f, bfr[2][0].f, d2); d2 = MFMA16(a1.f, bfr[2][1].f, d2);
    d3 = MFMA16(a0.f, bfr[3][0].f, d3); d3 = MFMA16(a1.f, bfr[3][1].f, d3);

    // epi: m = rt·relu(d), summed over the quad's 4 senders (D rows q*4+e)
    float m0 = 0.f, m1 = 0.f, m2 = 0.f, m3 = 0.f;
#pragma unroll
    for (int e = 0; e < 4; ++e) {
      m0 = fmaf(rtf[e], fmaxf(d0[e], 0.f), m0);
      m1 = fmaf(rtf[e], fmaxf(d1[e], 0.f), m1);
      m2 = fmaf(rtf[e], fmaxf(d2[e], 0.f), m2);
      m3 = fmaf(rtf[e], fmaxf(d3[e], 0.f), m3);
    }
    // reduce across quads (16 senders total); lane keeps o = q*16+r = lane
    m0 += __shfl_xor(m0, 16); m0 += __shfl_xor(m0, 32);
    m1 += __shfl_xor(m1, 16); m1 += __shfl_xor(m1, 32);
    m2 += __shfl_xor(m2, 16); m2 += __shfl_xor(m2, 32);
    m3 += __shfl_xor(m3, 16); m3 += __shfl_xor(m3, 32);
    const float aval = (q == 0) ? m0 : (q == 1) ? m1 : (q == 2) ? m2 : m3;
    AggP[w][ni][lane] = aval;
  }

  // ---- node weights (independent of AggP; overlap barrier)
  const int o = w * 16 + r;  // this wave's output column, layers 1 & 2
  Frag8 B1[2], B2[2];
#pragma unroll
  for (int ks = 0; ks < 2; ++ks) {
    const float* p1 = out1_w + o * 68 + 4 + ks * 32 + q * 8;
    const float4 c0 = *(const float4*)p1;
    const float4 c1 = *(const float4*)(p1 + 4);
    B1[ks].u[0] = pk16(c0.x, c0.y); B1[ks].u[1] = pk16(c0.z, c0.w);
    B1[ks].u[2] = pk16(c1.x, c1.y); B1[ks].u[3] = pk16(c1.z, c1.w);
    const float* p2 = out2_w + o * 64 + ks * 32 + q * 8;
    const float4 e0 = *(const float4*)p2;
    const float4 e1 = *(const float4*)(p2 + 4);
    B2[ks].u[0] = pk16(e0.x, e0.y); B2[ks].u[1] = pk16(e0.z, e0.w);
    B2[ks].u[2] = pk16(e1.x, e1.y); B2[ks].u[3] = pk16(e1.z, e1.w);
  }
  const float4 w1x = *(const float4*)(out1_w + o * 68);
  const float b1o = out1_b[o];
  const float b2o = out2_b[o];
  __syncthreads();

  // ---- combine partials: thread (w,lane) owns agg[ni=w][o=lane]
  {
    const float a = AggP[0][w][lane] + AggP[1][w][lane]
                  + AggP[2][w][lane] + AggP[3][w][lane];
    AggH[w * 68 + lane] = (_Float16)a;
  }
  __syncthreads();

  // ---------------- node phase (valid rows = 4 receivers) ----------------
  // Layer 1: h1[n][o] = relu(b1 + x[n]·w1x + agg[n]·W1k[o])
  {
    Frag8 A0, A1;
    A0.f = *(const f16x8*)(AggH + r * 68 + q * 8);       // rows 4..15 garbage, unused
    A1.f = *(const f16x8*)(AggH + r * 68 + 32 + q * 8);
    f32x4 d = {b1o, b1o, b1o, b1o};
    d = MFMA16(A0.f, B1[0].f, d);
    d = MFMA16(A1.f, B1[1].f, d);
    if (q == 0) {  // D rows 0..3 = receivers
#pragma unroll
      for (int reg = 0; reg < 4; ++reg) {
        const float4 x = Xl[reg];
        const float hv = d[reg] + x.x*w1x.x + x.y*w1x.y + x.z*w1x.z + x.w*w1x.w;
        H1L[reg * 68 + o] = (_Float16)fmaxf(hv, 0.f);
      }
    }
  }
  __syncthreads();

  // Layer 2: h2 = relu(b2 + h1·W2o^T)
  {
    Frag8 A0, A1;
    A0.f = *(const f16x8*)(H1L + r * 68 + q * 8);
    A1.f = *(const f16x8*)(H1L + r * 68 + 32 + q * 8);
    f32x4 d = {b2o, b2o, b2o, b2o};
    d = MFMA16(A0.f, B2[0].f, d);
    d = MFMA16(A1.f, B2[1].f, d);
    if (q == 0) {
#pragma unroll
      for (int reg = 0; reg < 4; ++reg)
        H2L[reg * 68 + o] = (_Float16)fmaxf(d[reg], 0.f);
    }
  }
  __syncthreads();

  // Layer 3 (wave 0): delta[n][dm] = b3[dm] + h2[n]·W3[dm]; out = x + delta
  if (w == 0) {
    Frag8 B3[2];
#pragma unroll
    for (int ks = 0; ks < 2; ++ks) {
      const float* p3 = out3_w + (r & 3) * 64 + ks * 32 + q * 8;
      const float4 c0 = *(const float4*)p3;
      const float4 c1 = *(const float4*)(p3 + 4);
      B3[ks].u[0] = pk16(c0.x, c0.y); B3[ks].u[1] = pk16(c0.z, c0.w);
      B3[ks].u[2] = pk16(c1.x, c1.y); B3[ks].u[3] = pk16(c1.z, c1.w);
    }
    Frag8 A0, A1;
    A0.f = *(const f16x8*)(H2L + r * 68 + q * 8);
    A1.f = *(const f16x8*)(H2L + r * 68 + 32 + q * 8);
    const float b3o = out3_b[r & 3];
    f32x4 d = {b3o, b3o, b3o, b3o};
    d = MFMA16(A0.f, B3[0].f, d);
    d = MFMA16(A1.f, B3[1].f, d);
    if (q == 0 && r < 4) {  // D[row=reg][col=r]: rows 0..3, cols 0..3 valid
      const float* xf = (const float*)Xl;
#pragma unroll
      for (int reg = 0; reg < 4; ++reg) {
        out[((b * NN + n_base + reg) * NTO + t) * ND + r] = xf[reg * 4 + r] + d[reg];
      }
    }
  }
}

extern "C" void kernel_launch(void* const* d_in, const int* in_sizes, int n_in,
                              void* d_out, int out_size, void* d_ws, size_t ws_size,
                              hipStream_t stream) {
  const float* inputs   = (const float*)d_in[0];
  const float* rel_type = (const float*)d_in[1];
  const float* fc1_w  = (const float*)d_in[4];
  const float* fc1_b  = (const float*)d_in[5];
  const float* fc2_w  = (const float*)d_in[6];
  const float* fc2_b  = (const float*)d_in[7];
  const float* out1_w = (const float*)d_in[8];
  const float* out1_b = (const float*)d_in[9];
  const float* out2_w = (const float*)d_in[10];
  const float* out2_b = (const float*)d_in[11];
  const float* out3_w = (const float*)d_in[12];
  const float* out3_b = (const float*)d_in[13];
  float* out = (float*)d_out;

  _Float16* Vg = (_Float16*)d_ws;                      // 8*49*64*64 f16 = 3.2 MB
  _Float16* Pg = Vg + NB * NTO * 64 * 64;              // same size, after Vg

  nri_prep_kernel<<<NB * NTO * 8, 64, 0, stream>>>(
      inputs, fc1_w, fc1_b, Vg, Pg);
  nri_main_kernel<<<NB * NTO * 16, 256, 0, stream>>>(
      inputs, rel_type, fc2_w, fc2_b,
      out1_w, out1_b, out2_w, out2_b, out3_w, out3_b, Vg, Pg, out);
}

// Round 8
// 151.869 us; speedup vs baseline: 1.1332x; 1.1332x over previous
//
#include <hip/hip_runtime.h>

// NRI MLP decoder, round 8: dense-precompute prep + deep fused main kernel.
// B=8, N=64, T=50 (49 used), D=4, H=64, K=2 (only relation i=1), E=4032.
// Prep (3136 blocks x 64): V[b,t,s,k], P[b,t,n,k] f16 tables; rt f32 table
//   rtg[b][n][s] (t-independent, self-edge=0); f16 weight tables W2f/B1f/B2f/B3f.
// Main (6272 blocks x 256): block=(b,t,4 receivers), wave=16-sender tile for
//   all 4. ALL edge inputs are hoisted 16B vector loads from L2-hot tables;
//   zero LDS/barriers in the edge phase. Cross-wave agg reduce in LDS, then
//   3-layer node MLP. mfma_f32_16x16x32_f16, fp32 accumulate.

#define NB 8
#define NN 64
#define NT 50
#define NTO 49
#define ND 4
#define NE 4032

typedef _Float16 f16x8 __attribute__((ext_vector_type(8)));
typedef _Float16 f16x2 __attribute__((ext_vector_type(2)));
typedef float f32x4 __attribute__((ext_vector_type(4)));

union Frag8 { unsigned u[4]; f16x8 f; f16x2 h[4]; };

__device__ __forceinline__ unsigned pk16(float lo, float hi) {
  return __builtin_bit_cast(unsigned, __builtin_amdgcn_cvt_pkrtz(lo, hi));
}

#define MFMA16(A, B, C) __builtin_amdgcn_mfma_f32_16x16x32_f16((A), (B), (C), 0, 0, 0)

// ws layout (bytes, all 16B-aligned)
#define WS_VG   0u
#define WS_PG   3211264u     // 8*49*64*64*2
#define WS_RTG  6422528u     // + same
#define WS_W2F  6553600u     // + 8*64*64*4
#define WS_B1F  6561792u
#define WS_B2F  6569984u
#define WS_B3F  6578176u

// ---------------------------------------------------------------------------
// Prep: bid -> (b, t, g). g<4: V rows; g>=4: P rows. t==0 blocks also build
// the rt table; (b==0,t==0) blocks also build the f16 weight tables.
// ---------------------------------------------------------------------------
__global__ __launch_bounds__(64) void nri_prep_kernel(
    const float* __restrict__ inputs,   // (B,N,T,D)
    const float* __restrict__ rel_type, // (B,1,E,2)
    const float* __restrict__ fc1_w,    // (2,64,8)
    const float* __restrict__ fc1_b,    // (2,64)
    const float* __restrict__ fc2_w,    // (2,64,64)
    const float* __restrict__ out1_w,   // (64,68)
    const float* __restrict__ out2_w,   // (64,64)
    const float* __restrict__ out3_w,   // (4,64)
    char* __restrict__ ws)
{
  _Float16* const Vg  = (_Float16*)(ws + WS_VG);
  _Float16* const Pg  = (_Float16*)(ws + WS_PG);
  float*    const rtg = (float*)   (ws + WS_RTG);
  _Float16* const W2f = (_Float16*)(ws + WS_W2F);
  _Float16* const B1f = (_Float16*)(ws + WS_B1F);
  _Float16* const B2f = (_Float16*)(ws + WS_B2F);
  _Float16* const B3f = (_Float16*)(ws + WS_B3F);

  const int bid = blockIdx.x;
  const int g   = bid & 7;
  const int t   = (bid >> 3) % NTO;
  const int b   = bid / (8 * NTO);
  const int k   = threadIdx.x;
  const int bt64 = (b * NTO + t) * 64;

  const float4 w1r = *(const float4*)(fc1_w + 512 + k * 8);
  const float4 w1s = *(const float4*)(fc1_w + 516 + k * 8);
  const float  b1k = fc1_b[64 + k];

  if (g < 4) {  // V rows s = g*16 .. g*16+15
#pragma unroll
    for (int ii = 0; ii < 16; ++ii) {
      const int s = g * 16 + ii;
      const float4 x = *(const float4*)(inputs + ((b * NN + s) * NT + t) * ND);
      Vg[(bt64 + s) * 64 + k] =
          (_Float16)(w1s.x*x.x + w1s.y*x.y + w1s.z*x.z + w1s.w*x.w);
    }
  } else {      // P rows n = (g-4)*16 ..
#pragma unroll
    for (int ii = 0; ii < 16; ++ii) {
      const int n = (g - 4) * 16 + ii;
      const float4 x = *(const float4*)(inputs + ((b * NN + n) * NT + t) * ND);
      Pg[(bt64 + n) * 64 + k] =
          (_Float16)(b1k + w1r.x*x.x + w1r.y*x.y + w1r.z*x.z + w1r.w*x.w);
    }
  }

  if (t == 0) {  // rt table: rows n = g*8 .. g*8+7; lane = s
#pragma unroll
    for (int ii = 0; ii < 8; ++ii) {
      const int n = g * 8 + ii;
      const int s = k;
      const float v = (s == n) ? 0.f
                    : rel_type[(b * NE + n * 63 + (s < n ? s : s - 1)) * 2 + 1];
      rtg[(b * 64 + n) * 64 + s] = v;
    }
  }
  if (b == 0 && t == 0) {  // weight tables (coalesced row reads, lane = k)
    if (g == 0) {
      for (int o = 0; o < 64; ++o)
        W2f[o * 64 + k] = (_Float16)fc2_w[4096 + o * 64 + k];
    } else if (g == 1) {
      for (int o = 0; o < 64; ++o)
        B1f[o * 64 + k] = (_Float16)out1_w[o * 68 + 4 + k];
    } else if (g == 2) {
      for (int o = 0; o < 64; ++o)
        B2f[o * 64 + k] = (_Float16)out2_w[o * 64 + k];
    } else if (g == 3) {
      for (int d = 0; d < 4; ++d)
        B3f[d * 64 + k] = (_Float16)out3_w[d * 64 + k];
    }
  }
}

// ---------------------------------------------------------------------------
// Main: bid -> (b, t, tile of 4 receivers).
// ---------------------------------------------------------------------------
__global__ __launch_bounds__(256) void nri_main_kernel(
    const float* __restrict__ inputs,
    const float* __restrict__ fc2_b,    // (2,64)
    const float* __restrict__ out1_w,   // (64,68) (x-part + bias use)
    const float* __restrict__ out1_b,
    const float* __restrict__ out2_b,
    const float* __restrict__ out3_b,
    const char* __restrict__ ws,
    float* __restrict__ out)            // (B,N,49,4)
{
  const _Float16* const Vg  = (const _Float16*)(ws + WS_VG);
  const _Float16* const Pg  = (const _Float16*)(ws + WS_PG);
  const float*    const rtg = (const float*)   (ws + WS_RTG);
  const _Float16* const W2f = (const _Float16*)(ws + WS_W2F);
  const _Float16* const B1f = (const _Float16*)(ws + WS_B1F);
  const _Float16* const B2f = (const _Float16*)(ws + WS_B2F);
  const _Float16* const B3f = (const _Float16*)(ws + WS_B3F);

  __shared__ float    AggP[4][4][64];   // [wave][ni][o] partial aggs
  __shared__ _Float16 AggH[16 * 68];    // rows 0..3 valid
  __shared__ _Float16 H1L[16 * 68];
  __shared__ _Float16 H2L[16 * 68];
  __shared__ float4   Xl[4];

  const int bid    = blockIdx.x;
  const int tile   = bid & 15;
  const int t      = (bid >> 4) % NTO;
  const int b      = bid / (16 * NTO);
  const int n_base = tile * 4;
  const int tid  = threadIdx.x;
  const int lane = tid & 63;
  const int w    = tid >> 6;
  const int q    = lane >> 4;
  const int r    = lane & 15;
  const int bt64 = (b * NTO + t) * 64;

  if (tid < 4)
    Xl[tid] = *(const float4*)(inputs + ((b * NN + n_base + tid) * NT + t) * ND);

  // ---- hoisted edge loads (all 16B vector loads, L2-hot tables) ----
  Frag8 va0, va1;                       // V for senders w*16 + r
  {
    const _Float16* vp = Vg + (bt64 + w * 16 + r) * 64 + q * 8;
    va0.f = *(const f16x8*)vp;
    va1.f = *(const f16x8*)(vp + 32);
  }
  Frag8 pa0[4], pa1[4];                 // P for the 4 receivers
#pragma unroll
  for (int ni = 0; ni < 4; ++ni) {
    const _Float16* pp = Pg + (bt64 + n_base + ni) * 64 + q * 8;
    pa0[ni].f = *(const f16x8*)pp;
    pa1[ni].f = *(const f16x8*)(pp + 32);
  }
  float4 rtv[4];                        // rt[n][senders w*16+q*4 ..]
#pragma unroll
  for (int ni = 0; ni < 4; ++ni)
    rtv[ni] = *(const float4*)(rtg + ((b * 64 + n_base + ni) * 64) + w * 16 + q * 4);

  Frag8 bfr[4][2];                      // W2 B-frags (f16 table, no pack)
  float b2l[4];
#pragma unroll
  for (int nt = 0; nt < 4; ++nt) {
    b2l[nt] = fc2_b[64 + nt * 16 + r];
    const _Float16* p = W2f + (nt * 16 + r) * 64 + q * 8;
    bfr[nt][0].f = *(const f16x8*)p;
    bfr[nt][1].f = *(const f16x8*)(p + 32);
  }

  // ---------------- edge phase (no LDS, no barriers) ----------------
#pragma unroll
  for (int ni = 0; ni < 4; ++ni) {
    const int n = n_base + ni;
    // h = relu(P + V), packed f16
    Frag8 a0, a1;
    const f16x2 z = {(_Float16)0.f, (_Float16)0.f};
#pragma unroll
    for (int j = 0; j < 4; ++j) {
      a0.h[j] = __builtin_elementwise_max((f16x2)(pa0[ni].h[j] + va0.h[j]), z);
      a1.h[j] = __builtin_elementwise_max((f16x2)(pa1[ni].h[j] + va1.h[j]), z);
    }

    f32x4 d0 = {b2l[0], b2l[0], b2l[0], b2l[0]};
    f32x4 d1 = {b2l[1], b2l[1], b2l[1], b2l[1]};
    f32x4 d2 = {b2l[2], b2l[2], b2l[2], b2l[2]};
    f32x4 d3 = {b2l[3], b2l[3], b2l[3], b2l[3]};
    d0 = MFMA16(a0.f, bfr[0][0].f, d0); d0 = MFMA16(a1.f, bfr[0][1].f, d0);
    d1 = MFMA16(a0.f, bfr[1][0].f, d1); d1 = MFMA16(a1.f, bfr[1][1].f, d1);
    d2 = MFMA16(a0.f, bfr[2][0].f, d2); d2 = MFMA16(a1.f, bfr[2][1].f, d2);
    d3 = MFMA16(a0.f, bfr[3][0].f, d3); d3 = MFMA16(a1.f, bfr[3][1].f, d3);

    // epi: m = rt·relu(d), summed over the quad's 4 senders (D rows q*4+e)
    const float rtf[4] = {rtv[ni].x, rtv[ni].y, rtv[ni].z, rtv[ni].w};
    float m0 = 0.f, m1 = 0.f, m2 = 0.f, m3 = 0.f;
#pragma unroll
    for (int e = 0; e < 4; ++e) {
      m0 = fmaf(rtf[e], fmaxf(d0[e], 0.f), m0);
      m1 = fmaf(rtf[e], fmaxf(d1[e], 0.f), m1);
      m2 = fmaf(rtf[e], fmaxf(d2[e], 0.f), m2);
      m3 = fmaf(rtf[e], fmaxf(d3[e], 0.f), m3);
    }
    // reduce across quads; lane keeps o = q*16+r = lane
    m0 += __shfl_xor(m0, 16); m0 += __shfl_xor(m0, 32);
    m1 += __shfl_xor(m1, 16); m1 += __shfl_xor(m1, 32);
    m2 += __shfl_xor(m2, 16); m2 += __shfl_xor(m2, 32);
    m3 += __shfl_xor(m3, 16); m3 += __shfl_xor(m3, 32);
    const float aval = (q == 0) ? m0 : (q == 1) ? m1 : (q == 2) ? m2 : m3;
    AggP[w][ni][lane] = aval;
  }

  // ---- node weights from f16 tables (independent of AggP)
  const int o = w * 16 + r;             // output column, layers 1 & 2
  Frag8 B1[2], B2[2];
  {
    const _Float16* p1 = B1f + o * 64 + q * 8;
    B1[0].f = *(const f16x8*)p1;
    B1[1].f = *(const f16x8*)(p1 + 32);
    const _Float16* p2 = B2f + o * 64 + q * 8;
    B2[0].f = *(const f16x8*)p2;
    B2[1].f = *(const f16x8*)(p2 + 32);
  }
  const float4 w1x = *(const float4*)(out1_w + o * 68);
  const float b1o = out1_b[o];
  const float b2o = out2_b[o];
  __syncthreads();

  // ---- combine partials: thread (w,lane) owns agg[ni=w][o=lane]
  {
    const float a = AggP[0][w][lane] + AggP[1][w][lane]
                  + AggP[2][w][lane] + AggP[3][w][lane];
    AggH[w * 68 + lane] = (_Float16)a;
  }
  __syncthreads();

  // ---------------- node phase (valid rows = 4 receivers) ----------------
  // Layer 1: h1[n][o] = relu(b1 + x[n]·w1x + agg[n]·W1k[o])
  {
    Frag8 A0, A1;
    A0.f = *(const f16x8*)(AggH + r * 68 + q * 8);
    A1.f = *(const f16x8*)(AggH + r * 68 + 32 + q * 8);
    f32x4 d = {b1o, b1o, b1o, b1o};
    d = MFMA16(A0.f, B1[0].f, d);
    d = MFMA16(A1.f, B1[1].f, d);
    if (q == 0) {
#pragma unroll
      for (int reg = 0; reg < 4; ++reg) {
        const float4 x = Xl[reg];
        const float hv = d[reg] + x.x*w1x.x + x.y*w1x.y + x.z*w1x.z + x.w*w1x.w;
        H1L[reg * 68 + o] = (_Float16)fmaxf(hv, 0.f);
      }
    }
  }
  __syncthreads();

  // Layer 2
  {
    Frag8 A0, A1;
    A0.f = *(const f16x8*)(H1L + r * 68 + q * 8);
    A1.f = *(const f16x8*)(H1L + r * 68 + 32 + q * 8);
    f32x4 d = {b2o, b2o, b2o, b2o};
    d = MFMA16(A0.f, B2[0].f, d);
    d = MFMA16(A1.f, B2[1].f, d);
    if (q == 0) {
#pragma unroll
      for (int reg = 0; reg < 4; ++reg)
        H2L[reg * 68 + o] = (_Float16)fmaxf(d[reg], 0.f);
    }
  }
  __syncthreads();

  // Layer 3 (wave 0)
  if (w == 0) {
    Frag8 B3[2];
    {
      const _Float16* p3 = B3f + (r & 3) * 64 + q * 8;
      B3[0].f = *(const f16x8*)p3;
      B3[1].f = *(const f16x8*)(p3 + 32);
    }
    Frag8 A0, A1;
    A0.f = *(const f16x8*)(H2L + r * 68 + q * 8);
    A1.f = *(const f16x8*)(H2L + r * 68 + 32 + q * 8);
    const float b3o = out3_b[r & 3];
    f32x4 d = {b3o, b3o, b3o, b3o};
    d = MFMA16(A0.f, B3[0].f, d);
    d = MFMA16(A1.f, B3[1].f, d);
    if (q == 0 && r < 4) {
      const float* xf = (const float*)Xl;
#pragma unroll
      for (int reg = 0; reg < 4; ++reg) {
        out[((b * NN + n_base + reg) * NTO + t) * ND + r] = xf[reg * 4 + r] + d[reg];
      }
    }
  }
}

extern "C" void kernel_launch(void* const* d_in, const int* in_sizes, int n_in,
                              void* d_out, int out_size, void* d_ws, size_t ws_size,
                              hipStream_t stream) {
  const float* inputs   = (const float*)d_in[0];
  const float* rel_type = (const float*)d_in[1];
  const float* fc1_w  = (const float*)d_in[4];
  const float* fc1_b  = (const float*)d_in[5];
  const float* fc2_w  = (const float*)d_in[6];
  const float* fc2_b  = (const float*)d_in[7];
  const float* out1_w = (const float*)d_in[8];
  const float* out1_b = (const float*)d_in[9];
  const float* out2_w = (const float*)d_in[10];
  const float* out2_b = (const float*)d_in[11];
  const float* out3_w = (const float*)d_in[12];
  const float* out3_b = (const float*)d_in[13];
  float* out = (float*)d_out;
  char* ws = (char*)d_ws;

  nri_prep_kernel<<<NB * NTO * 8, 64, 0, stream>>>(
      inputs, rel_type, fc1_w, fc1_b, fc2_w, out1_w, out2_w, out3_w, ws);
  nri_main_kernel<<<NB * NTO * 16, 256, 0, stream>>>(
      inputs, fc2_b, out1_w, out1_b, out2_b, out3_b, ws, out);
}

// Round 9
// 131.441 us; speedup vs baseline: 1.3093x; 1.1554x over previous
//
#include <hip/hip_runtime.h>

// NRI MLP decoder, round 9: round-6 work shape + round-8 input pipeline.
// B=8, N=64, T=50 (49 used), D=4, H=64, K=2 (only relation i=1), E=4032.
// Prep (3136 x 64): f16 tables V[b,t,s,k], P[b,t,n,k]; dense f32 rt table
//   rtg[b][n][s] (t-independent, self-edge=0); f16 weight tables.
// Main (1568 x 256): block=(b,t,16 receivers); wave = 4 receivers x all 64
//   senders. V frags for all 4 sender tiles hoisted into regs; edge inner
//   loop is pure-register (no LDS, no global, no barrier). Node MLP = 3 MFMA
//   layers over the block's 16 rows via f16 LDS (stride 68).
// mfma_f32_16x16x32_f16, fp32 accumulate.

#define NB 8
#define NN 64
#define NT 50
#define NTO 49
#define ND 4
#define NE 4032

typedef _Float16 f16x8 __attribute__((ext_vector_type(8)));
typedef _Float16 f16x2 __attribute__((ext_vector_type(2)));
typedef float f32x4 __attribute__((ext_vector_type(4)));

union Frag8 { unsigned u[4]; f16x8 f; f16x2 h[4]; };

#define MFMA16(A, B, C) __builtin_amdgcn_mfma_f32_16x16x32_f16((A), (B), (C), 0, 0, 0)

// ws layout (bytes, 16B-aligned)
#define WS_VG   0u
#define WS_PG   3211264u     // 8*49*64*64*2
#define WS_RTG  6422528u     // + same
#define WS_W2F  6553600u     // + 8*64*64*4
#define WS_B1F  6561792u
#define WS_B2F  6569984u
#define WS_B3F  6578176u

// ---------------------------------------------------------------------------
// Prep: bid -> (b, t, g). g<4: V rows; g>=4: P rows. t==0 blocks build rt
// table; (b==0,t==0) blocks build f16 weight tables.
// ---------------------------------------------------------------------------
__global__ __launch_bounds__(64) void nri_prep_kernel(
    const float* __restrict__ inputs,   // (B,N,T,D)
    const float* __restrict__ rel_type, // (B,1,E,2)
    const float* __restrict__ fc1_w,    // (2,64,8)
    const float* __restrict__ fc1_b,    // (2,64)
    const float* __restrict__ fc2_w,    // (2,64,64)
    const float* __restrict__ out1_w,   // (64,68)
    const float* __restrict__ out2_w,   // (64,64)
    const float* __restrict__ out3_w,   // (4,64)
    char* __restrict__ ws)
{
  _Float16* const Vg  = (_Float16*)(ws + WS_VG);
  _Float16* const Pg  = (_Float16*)(ws + WS_PG);
  float*    const rtg = (float*)   (ws + WS_RTG);
  _Float16* const W2f = (_Float16*)(ws + WS_W2F);
  _Float16* const B1f = (_Float16*)(ws + WS_B1F);
  _Float16* const B2f = (_Float16*)(ws + WS_B2F);
  _Float16* const B3f = (_Float16*)(ws + WS_B3F);

  const int bid = blockIdx.x;
  const int g   = bid & 7;
  const int t   = (bid >> 3) % NTO;
  const int b   = bid / (8 * NTO);
  const int k   = threadIdx.x;
  const int bt64 = (b * NTO + t) * 64;

  const float4 w1r = *(const float4*)(fc1_w + 512 + k * 8);
  const float4 w1s = *(const float4*)(fc1_w + 516 + k * 8);
  const float  b1k = fc1_b[64 + k];

  if (g < 4) {
#pragma unroll
    for (int ii = 0; ii < 16; ++ii) {
      const int s = g * 16 + ii;
      const float4 x = *(const float4*)(inputs + ((b * NN + s) * NT + t) * ND);
      Vg[(bt64 + s) * 64 + k] =
          (_Float16)(w1s.x*x.x + w1s.y*x.y + w1s.z*x.z + w1s.w*x.w);
    }
  } else {
#pragma unroll
    for (int ii = 0; ii < 16; ++ii) {
      const int n = (g - 4) * 16 + ii;
      const float4 x = *(const float4*)(inputs + ((b * NN + n) * NT + t) * ND);
      Pg[(bt64 + n) * 64 + k] =
          (_Float16)(b1k + w1r.x*x.x + w1r.y*x.y + w1r.z*x.z + w1r.w*x.w);
    }
  }

  if (t == 0) {  // rt table: rows n = g*8 .. g*8+7; lane = s
#pragma unroll
    for (int ii = 0; ii < 8; ++ii) {
      const int n = g * 8 + ii;
      const int s = k;
      const float v = (s == n) ? 0.f
                    : rel_type[(b * NE + n * 63 + (s < n ? s : s - 1)) * 2 + 1];
      rtg[(b * 64 + n) * 64 + s] = v;
    }
  }
  if (b == 0 && t == 0) {
    if (g == 0) {
      for (int o = 0; o < 64; ++o)
        W2f[o * 64 + k] = (_Float16)fc2_w[4096 + o * 64 + k];
    } else if (g == 1) {
      for (int o = 0; o < 64; ++o)
        B1f[o * 64 + k] = (_Float16)out1_w[o * 68 + 4 + k];
    } else if (g == 2) {
      for (int o = 0; o < 64; ++o)
        B2f[o * 64 + k] = (_Float16)out2_w[o * 64 + k];
    } else if (g == 3) {
      for (int d = 0; d < 4; ++d)
        B3f[d * 64 + k] = (_Float16)out3_w[d * 64 + k];
    }
  }
}

// ---------------------------------------------------------------------------
// Main: bid -> (b, t, 16-receiver tile). Wave w owns receivers w*4..w*4+3.
// ---------------------------------------------------------------------------
__global__ __launch_bounds__(256) void nri_main_kernel(
    const float* __restrict__ inputs,
    const float* __restrict__ fc2_b,    // (2,64)
    const float* __restrict__ out1_w,   // (64,68)
    const float* __restrict__ out1_b,
    const float* __restrict__ out2_b,
    const float* __restrict__ out3_b,
    const char* __restrict__ ws,
    float* __restrict__ out)            // (B,N,49,4)
{
  const _Float16* const Vg  = (const _Float16*)(ws + WS_VG);
  const _Float16* const Pg  = (const _Float16*)(ws + WS_PG);
  const float*    const rtg = (const float*)   (ws + WS_RTG);
  const _Float16* const W2f = (const _Float16*)(ws + WS_W2F);
  const _Float16* const B1f = (const _Float16*)(ws + WS_B1F);
  const _Float16* const B2f = (const _Float16*)(ws + WS_B2F);
  const _Float16* const B3f = (const _Float16*)(ws + WS_B3F);

  __shared__ _Float16 AggH[16 * 68];
  __shared__ _Float16 H1L[16 * 68];
  __shared__ _Float16 H2L[16 * 68];
  __shared__ float4   Xl[16];

  const int bid    = blockIdx.x;
  const int tile   = bid & 3;
  const int t      = (bid >> 2) % NTO;
  const int b      = bid / (4 * NTO);
  const int n_base = tile * 16;
  const int tid  = threadIdx.x;
  const int lane = tid & 63;
  const int w    = tid >> 6;
  const int q    = lane >> 4;
  const int r    = lane & 15;
  const int bt64 = (b * NTO + t) * 64;

  if (tid < 16)
    Xl[tid] = *(const float4*)(inputs + ((b * NN + n_base + tid) * NT + t) * ND);

  // ---- hoisted loads: V frags for all 4 sender tiles (pure-reg edge loop)
  Frag8 va[4][2];
#pragma unroll
  for (int st = 0; st < 4; ++st) {
    const _Float16* vp = Vg + (bt64 + st * 16 + r) * 64 + q * 8;
    va[st][0].f = *(const f16x8*)vp;
    va[st][1].f = *(const f16x8*)(vp + 32);
  }
  // W2 B-frags + bias
  Frag8 bfr[4][2];
  float b2l[4];
#pragma unroll
  for (int nt = 0; nt < 4; ++nt) {
    b2l[nt] = fc2_b[64 + nt * 16 + r];
    const _Float16* p = W2f + (nt * 16 + r) * 64 + q * 8;
    bfr[nt][0].f = *(const f16x8*)p;
    bfr[nt][1].f = *(const f16x8*)(p + 32);
  }
  // node weights (used after the barrier; loads overlap edge compute)
  const int o = w * 16 + r;
  Frag8 B1[2], B2[2];
  {
    const _Float16* p1 = B1f + o * 64 + q * 8;
    B1[0].f = *(const f16x8*)p1;
    B1[1].f = *(const f16x8*)(p1 + 32);
    const _Float16* p2 = B2f + o * 64 + q * 8;
    B2[0].f = *(const f16x8*)p2;
    B2[1].f = *(const f16x8*)(p2 + 32);
  }
  const float4 w1x = *(const float4*)(out1_w + o * 68);
  const float b1o = out1_b[o];
  const float b2o = out2_b[o];

  // ---------------- edge phase: 4 receivers x 64 senders, reg-only ----------
#pragma unroll 1
  for (int np = 0; np < 4; ++np) {
    const int ni = w * 4 + np;
    const int n  = n_base + ni;
    Frag8 pa0, pa1;
    {
      const _Float16* pp = Pg + (bt64 + n) * 64 + q * 8;
      pa0.f = *(const f16x8*)pp;
      pa1.f = *(const f16x8*)(pp + 32);
    }
    float4 rtv[4];
#pragma unroll
    for (int st = 0; st < 4; ++st)
      rtv[st] = *(const float4*)(rtg + (b * 64 + n) * 64 + st * 16 + q * 4);

    float m0 = 0.f, m1 = 0.f, m2 = 0.f, m3 = 0.f;
#pragma unroll
    for (int st = 0; st < 4; ++st) {
      // h = relu(P + V), packed f16, all operands in registers
      Frag8 a0, a1;
      const f16x2 z = {(_Float16)0.f, (_Float16)0.f};
#pragma unroll
      for (int j = 0; j < 4; ++j) {
        a0.h[j] = __builtin_elementwise_max((f16x2)(pa0.h[j] + va[st][0].h[j]), z);
        a1.h[j] = __builtin_elementwise_max((f16x2)(pa1.h[j] + va[st][1].h[j]), z);
      }

      f32x4 d0 = {b2l[0], b2l[0], b2l[0], b2l[0]};
      f32x4 d1 = {b2l[1], b2l[1], b2l[1], b2l[1]};
      f32x4 d2 = {b2l[2], b2l[2], b2l[2], b2l[2]};
      f32x4 d3 = {b2l[3], b2l[3], b2l[3], b2l[3]};
      d0 = MFMA16(a0.f, bfr[0][0].f, d0); d0 = MFMA16(a1.f, bfr[0][1].f, d0);
      d1 = MFMA16(a0.f, bfr[1][0].f, d1); d1 = MFMA16(a1.f, bfr[1][1].f, d1);
      d2 = MFMA16(a0.f, bfr[2][0].f, d2); d2 = MFMA16(a1.f, bfr[2][1].f, d2);
      d3 = MFMA16(a0.f, bfr[3][0].f, d3); d3 = MFMA16(a1.f, bfr[3][1].f, d3);

      const float rtf[4] = {rtv[st].x, rtv[st].y, rtv[st].z, rtv[st].w};
#pragma unroll
      for (int e = 0; e < 4; ++e) {
        m0 = fmaf(rtf[e], fmaxf(d0[e], 0.f), m0);
        m1 = fmaf(rtf[e], fmaxf(d1[e], 0.f), m1);
        m2 = fmaf(rtf[e], fmaxf(d2[e], 0.f), m2);
        m3 = fmaf(rtf[e], fmaxf(d3[e], 0.f), m3);
      }
    }
    // cross-quad reduce (each quad summed 16 senders); lane keeps o = lane
    m0 += __shfl_xor(m0, 16); m0 += __shfl_xor(m0, 32);
    m1 += __shfl_xor(m1, 16); m1 += __shfl_xor(m1, 32);
    m2 += __shfl_xor(m2, 16); m2 += __shfl_xor(m2, 32);
    m3 += __shfl_xor(m3, 16); m3 += __shfl_xor(m3, 32);
    const float aval = (q == 0) ? m0 : (q == 1) ? m1 : (q == 2) ? m2 : m3;
    AggH[ni * 68 + lane] = (_Float16)aval;
  }
  __syncthreads();

  // ---------------- node phase (16 valid rows) ----------------
  // Layer 1: h1[n][o] = relu(b1 + x[n]·w1x + agg[n]·W1k[o])
  {
    Frag8 A0, A1;
    A0.f = *(const f16x8*)(AggH + r * 68 + q * 8);
    A1.f = *(const f16x8*)(AggH + r * 68 + 32 + q * 8);
    f32x4 d = {b1o, b1o, b1o, b1o};
    d = MFMA16(A0.f, B1[0].f, d);
    d = MFMA16(A1.f, B1[1].f, d);
#pragma unroll
    for (int reg = 0; reg < 4; ++reg) {
      const int n = q * 4 + reg;
      const float4 x = Xl[n];
      const float hv = d[reg] + x.x*w1x.x + x.y*w1x.y + x.z*w1x.z + x.w*w1x.w;
      H1L[n * 68 + o] = (_Float16)fmaxf(hv, 0.f);
    }
  }
  __syncthreads();

  // Layer 2
  {
    Frag8 A0, A1;
    A0.f = *(const f16x8*)(H1L + r * 68 + q * 8);
    A1.f = *(const f16x8*)(H1L + r * 68 + 32 + q * 8);
    f32x4 d = {b2o, b2o, b2o, b2o};
    d = MFMA16(A0.f, B2[0].f, d);
    d = MFMA16(A1.f, B2[1].f, d);
#pragma unroll
    for (int reg = 0; reg < 4; ++reg) {
      const int n = q * 4 + reg;
      H2L[n * 68 + o] = (_Float16)fmaxf(d[reg], 0.f);
    }
  }
  __syncthreads();

  // Layer 3 (wave 0)
  if (w == 0) {
    Frag8 B3[2];
    {
      const _Float16* p3 = B3f + (r & 3) * 64 + q * 8;
      B3[0].f = *(const f16x8*)p3;
      B3[1].f = *(const f16x8*)(p3 + 32);
    }
    Frag8 A0, A1;
    A0.f = *(const f16x8*)(H2L + r * 68 + q * 8);
    A1.f = *(const f16x8*)(H2L + r * 68 + 32 + q * 8);
    const float b3o = out3_b[r & 3];
    f32x4 d = {b3o, b3o, b3o, b3o};
    d = MFMA16(A0.f, B3[0].f, d);
    d = MFMA16(A1.f, B3[1].f, d);
    if (r < 4) {  // D[row=q*4+reg][col=r]: all 16 rows valid, cols 0..3
      const float* xf = (const float*)Xl;
#pragma unroll
      for (int reg = 0; reg < 4; ++reg) {
        const int n = q * 4 + reg;
        out[((b * NN + n_base + n) * NTO + t) * ND + r] = xf[n * 4 + r] + d[reg];
      }
    }
  }
}

extern "C" void kernel_launch(void* const* d_in, const int* in_sizes, int n_in,
                              void* d_out, int out_size, void* d_ws, size_t ws_size,
                              hipStream_t stream) {
  const float* inputs   = (const float*)d_in[0];
  const float* rel_type = (const float*)d_in[1];
  const float* fc1_w  = (const float*)d_in[4];
  const float* fc1_b  = (const float*)d_in[5];
  const float* fc2_w  = (const float*)d_in[6];
  const float* fc2_b  = (const float*)d_in[7];
  const float* out1_w = (const float*)d_in[8];
  const float* out1_b = (const float*)d_in[9];
  const float* out2_w = (const float*)d_in[10];
  const float* out2_b = (const float*)d_in[11];
  const float* out3_w = (const float*)d_in[12];
  const float* out3_b = (const float*)d_in[13];
  float* out = (float*)d_out;
  char* ws = (char*)d_ws;

  nri_prep_kernel<<<NB * NTO * 8, 64, 0, stream>>>(
      inputs, rel_type, fc1_w, fc1_b, fc2_w, out1_w, out2_w, out3_w, ws);
  nri_main_kernel<<<NB * NTO * 4, 256, 0, stream>>>(
      inputs, fc2_b, out1_w, out1_b, out2_b, out3_b, ws, out);
}